// Round 8
// baseline (326.752 us; speedup 1.0000x reference)
//
#include <hip/hip_runtime.h>
#include <hip/hip_fp16.h>
#include <math.h>

#define NN 50000
#define NE 500000
#define DD 128
#define EPSV 1e-12f
#define SCC 196        // scan chunk per block (256*196 >= NN)
#define NWAVE 8192     // waves in fused kernel

typedef short short8 __attribute__((ext_vector_type(8)));
typedef _Float16 f16x8 __attribute__((ext_vector_type(8)));
typedef float f32x4 __attribute__((ext_vector_type(4)));

__device__ __forceinline__ ushort f2bf(float f) {
    return __builtin_bit_cast(unsigned short, (__bf16)f);
}
__device__ __forceinline__ ushort f2h(float f) {
    return __builtin_bit_cast(unsigned short, (_Float16)f);
}
__device__ __forceinline__ float bf2f(unsigned u) {
    union { unsigned u; float f; } v; v.u = u << 16;
    return v.f;
}
__device__ __forceinline__ float bf2f_hi(unsigned u) {
    union { unsigned u; float f; } v; v.u = u & 0xffff0000u;
    return v.f;
}

// ---------------- Kernel 0: weight composition (fp32) ----------------
__global__ __launch_bounds__(256) void compose_kernel(
    const float* __restrict__ Wsrc, const float* __restrict__ Wdst,
    const float* __restrict__ Wa1, const float* __restrict__ Wpos,
    const float* __restrict__ bpos, const float* __restrict__ ba1,
    float* __restrict__ W1s, float* __restrict__ W1d,
    float* __restrict__ Wp1, float* __restrict__ b1eff)
{
    __shared__ float a1[128 * 8];
    const int t = threadIdx.x;
    const int j0 = blockIdx.x * 8;
    for (int idx = t; idx < 1024; idx += 256) {
        int i = idx >> 3, jl = idx & 7;
        a1[idx] = Wa1[i * 128 + j0 + jl];
    }
    __syncthreads();
    const int jl = t & 7, k0 = t >> 3;
#pragma unroll 1
    for (int kb = 0; kb < 4; ++kb) {
        int k = kb * 32 + k0;
        float s1 = 0.f, s2 = 0.f;
        for (int i = 0; i < 128; ++i) {
            float w = a1[i * 8 + jl];
            s1 = fmaf(Wsrc[k * 128 + i], w, s1);
            s2 = fmaf(Wdst[k * 128 + i], w, s2);
        }
        W1s[k * 128 + j0 + jl] = s1;
        W1d[k * 128 + j0 + jl] = s2;
    }
    if (t < 32) {
        int d = t >> 3, j = j0 + (t & 7);
        float s = 0.f;
        if (d < 3) {
            for (int i = 0; i < 128; ++i) s = fmaf(Wpos[d * 128 + i], a1[i * 8 + (t & 7)], s);
            Wp1[d * 128 + j] = s;
        } else {
            for (int i = 0; i < 128; ++i) s = fmaf(bpos[i], a1[i * 8 + (t & 7)], s);
            b1eff[j] = s + ba1[j];
        }
    }
}

// ---------------- Kernel 1: node GEMMs, 3 phases fused ----------------
// y=0: Uh(fp16) = x@W1s + pos@Wp1 + b1eff
// y=1: Vh(fp16) = x@W1d + pos@Wp1
// y=2: Xc2(packed bf16 dword (ch,ch+64)) = x@W - pos@Wpos
__global__ __launch_bounds__(256) void node_gemm(
    const float* __restrict__ x, const float* __restrict__ pos,
    const float* __restrict__ W, const float* __restrict__ W1s,
    const float* __restrict__ W1d, const float* __restrict__ Wpos,
    const float* __restrict__ Wp1, const float* __restrict__ b1eff,
    ushort* __restrict__ Uh, ushort* __restrict__ Vh, unsigned* __restrict__ Xc2)
{
    __shared__ ushort wsm[16384];
    const int t = threadIdx.x;
    const int w = t >> 6;
    const int l = t & 63;
    const int g = l >> 4;
    const int low = l & 15;

    const int n0 = (blockIdx.x * 4 + w) * 16;
    const int rowi = min(n0 + low, NN - 1);

    short8 af[4];
#pragma unroll
    for (int kc = 0; kc < 4; ++kc) {
        const float* xp = x + (size_t)rowi * 128 + kc * 32 + g * 8;
        float4 a0 = *(const float4*)xp;
        float4 a1 = *(const float4*)(xp + 4);
        short8 v;
        v[0] = (short)f2bf(a0.x); v[1] = (short)f2bf(a0.y);
        v[2] = (short)f2bf(a0.z); v[3] = (short)f2bf(a0.w);
        v[4] = (short)f2bf(a1.x); v[5] = (short)f2bf(a1.y);
        v[6] = (short)f2bf(a1.z); v[7] = (short)f2bf(a1.w);
        af[kc] = v;
    }
    float posr[4][3];
#pragma unroll
    for (int r = 0; r < 4; ++r) {
        int node = min(n0 + g * 4 + r, NN - 1);
        posr[r][0] = pos[node * 3]; posr[r][1] = pos[node * 3 + 1]; posr[r][2] = pos[node * 3 + 2];
    }

#pragma unroll 1
    for (int y = 0; y < 3; ++y) {
        const float* Wsel = (y == 0) ? W1s : (y == 1) ? W1d : W;
        const float* wps  = (y < 2) ? Wp1 : Wpos;

        for (int gi = t; gi < 2048; gi += 256) {
            int j = gi & 127, k8 = gi >> 7;
            short8 v;
#pragma unroll
            for (int i = 0; i < 8; ++i)
                v[i] = (short)f2bf(Wsel[(k8 * 8 + i) * 128 + j]);
            *(short8*)&wsm[j * 128 + ((k8 ^ (j & 15)) << 3)] = v;
        }
        float wp0[8], wp1v[8], wp2[8], bpv[8];
#pragma unroll
        for (int nb = 0; nb < 8; ++nb) {
            int ch = nb * 16 + low;
            wp0[nb] = wps[ch]; wp1v[nb] = wps[128 + ch]; wp2[nb] = wps[256 + ch];
            bpv[nb] = (y == 0) ? b1eff[ch] : 0.f;
        }
        __syncthreads();

        f32x4 acc[8];
#pragma unroll
        for (int nb = 0; nb < 8; ++nb) { acc[nb][0]=0.f; acc[nb][1]=0.f; acc[nb][2]=0.f; acc[nb][3]=0.f; }
#pragma unroll
        for (int nb = 0; nb < 8; ++nb) {
            int j = nb * 16 + low;
#pragma unroll
            for (int kc = 0; kc < 4; ++kc) {
                short8 bf = *(const short8*)&wsm[j * 128 + (((kc * 4 + g) ^ low) << 3)];
                acc[nb] = __builtin_amdgcn_mfma_f32_16x16x32_bf16(af[kc], bf, acc[nb], 0, 0, 0);
            }
        }

#pragma unroll
        for (int r = 0; r < 4; ++r) {
            int node = n0 + g * 4 + r;
            if (node < NN) {
                float p0 = posr[r][0], p1 = posr[r][1], p2 = posr[r][2];
                if (y < 2) {
#pragma unroll
                    for (int nb = 0; nb < 8; ++nb) {
                        float pterm = p0 * wp0[nb] + p1 * wp1v[nb] + p2 * wp2[nb];
                        size_t idx = (size_t)node * 128 + nb * 16 + low;
                        if (y == 0) Uh[idx] = f2h(acc[nb][r] + pterm + bpv[nb]);
                        else        Vh[idx] = f2h(acc[nb][r] + pterm);
                    }
                } else {
#pragma unroll
                    for (int nb = 0; nb < 4; ++nb) {
                        float ptl = p0 * wp0[nb] + p1 * wp1v[nb] + p2 * wp2[nb];
                        float pth = p0 * wp0[nb+4] + p1 * wp1v[nb+4] + p2 * wp2[nb+4];
                        Xc2[(size_t)node * 64 + nb * 16 + low] =
                            (unsigned)f2bf(acc[nb][r] - ptl) | ((unsigned)f2bf(acc[nb+4][r] - pth) << 16);
                    }
                }
            }
        }
        __syncthreads();
    }
}

// ---------------- CSR build ----------------
__global__ __launch_bounds__(256) void hist_kernel(const int* __restrict__ ei, int* __restrict__ counts)
{
    int e = blockIdx.x * 256 + threadIdx.x;
    if (e < NE) atomicAdd(&counts[ei[2 * e]], 1);
}

__global__ __launch_bounds__(256) void csr_partial(const int* __restrict__ counts, int* __restrict__ partial)
{
    __shared__ int red[256];
    const int b = blockIdx.x, t = threadIdx.x;
    const int idx = b * SCC + t;
    red[t] = (t < SCC && idx < NN) ? counts[idx] : 0;
    __syncthreads();
#pragma unroll
    for (int d = 128; d > 0; d >>= 1) {
        if (t < d) red[t] += red[t + d];
        __syncthreads();
    }
    if (t == 0) partial[b] = red[0];
}

__global__ __launch_bounds__(256) void csr_scanp(int* __restrict__ partial, int* __restrict__ offsets)
{
    __shared__ int s[256];
    const int t = threadIdx.x;
    int v = partial[t];
    s[t] = v;
    __syncthreads();
    for (int d = 1; d < 256; d <<= 1) {
        int u = (t >= d) ? s[t - d] : 0;
        __syncthreads();
        s[t] += u;
        __syncthreads();
    }
    partial[t] = s[t] - v;
    if (t == 255) offsets[NN] = s[255];
}

__global__ __launch_bounds__(256) void csr_distribute(
    const int* __restrict__ counts, const int* __restrict__ partial,
    int* __restrict__ offsets, int* __restrict__ cursor)
{
    __shared__ int s[256];
    const int b = blockIdx.x, t = threadIdx.x;
    const int idx = b * SCC + t;
    int v = (t < SCC && idx < NN) ? counts[idx] : 0;
    s[t] = v;
    __syncthreads();
    for (int d = 1; d < 256; d <<= 1) {
        int u = (t >= d) ? s[t - d] : 0;
        __syncthreads();
        s[t] += u;
        __syncthreads();
    }
    if (t < SCC && idx < NN) {
        int off = partial[b] + s[t] - v;
        offsets[idx] = off;
        cursor[idx] = off;
    }
}

__global__ __launch_bounds__(256) void scatter_kernel(const int* __restrict__ ei,
                                                      int* __restrict__ cursor,
                                                      int2* __restrict__ rc2)
{
    int e = blockIdx.x * 256 + threadIdx.x;
    if (e < NE) {
        int r = ei[2 * e];
        int c = ei[2 * e + 1];
        int p = atomicAdd(&cursor[r], 1);
        rc2[p] = make_int2(r, c);
    }
}

// ---------------- wave range partition (node-aligned) ----------------
__global__ __launch_bounds__(256) void range_kernel(const int* __restrict__ offsets, int* __restrict__ sn)
{
    int w = blockIdx.x * 256 + threadIdx.x;
    if (w > NWAVE) return;
    if (w == NWAVE) { sn[w] = NN; return; }
    int target = (int)(((long long)w * NE) / NWAVE);
    int lo = 0, hi = NN;
    while (lo < hi) {
        int mid = (lo + hi) >> 1;
        if (offsets[mid] >= target) hi = mid; else lo = mid + 1;
    }
    sn[w] = lo;
}

// ---------------- Fused edge kernel: alpha MFMA + exp + aggregate ----------------
// Wave owns nodes [sn[w], sn[w+1]): per 16-edge tile computes exp(alpha) via f16 MFMA,
// transposes through wave-private LDS, then serially accumulates coalesced Xc2 rows,
// flushing each completed node to out. No intermediate HBM arrays.
__global__ __launch_bounds__(256) void fused_edge(
    const ushort* __restrict__ Uh, const ushort* __restrict__ Vh,
    const float* __restrict__ Wa2, const float* __restrict__ ba2,
    const float* __restrict__ pos, const float* __restrict__ Wpos,
    const float* __restrict__ bpos,
    const int2* __restrict__ rc2, const int* __restrict__ offsets,
    const int* __restrict__ sn,
    const unsigned* __restrict__ Xc2, float* __restrict__ out)
{
    __shared__ ushort wl[16384];            // Wa2 fp16 swizzled (32 KB)
    __shared__ unsigned wtile[4][16 * 64];  // per-wave exp(alpha) tile (4 KB each)

    const int t = threadIdx.x;
    const int w = t >> 6;
    const int l = t & 63;
    const int g = l >> 4;
    const int low = l & 15;

    for (int gi = t; gi < 2048; gi += 256) {
        int j = gi & 127, k8 = gi >> 7;
        short8 v;
#pragma unroll
        for (int i = 0; i < 8; ++i)
            v[i] = (short)f2h(Wa2[(k8 * 8 + i) * 128 + j]);
        *(short8*)&wl[j * 128 + ((k8 ^ (j & 15)) << 3)] = v;
    }
    float b2v[8];
#pragma unroll
    for (int nb = 0; nb < 8; ++nb) b2v[nb] = ba2[nb * 16 + low];
    // aggregation-phase per-lane channel constants (ch=l, ch=l+64)
    const float wa0 = Wpos[l], wa1 = Wpos[128 + l], wa2c = Wpos[256 + l];
    const float wb0 = Wpos[64 + l], wb1 = Wpos[192 + l], wb2 = Wpos[320 + l];
    const float bp0 = bpos[l], bp1 = bpos[64 + l];
    __syncthreads();

    const int wv = blockIdx.x * 4 + w;
    const int nA = sn[wv], nB = sn[wv + 1];
    const int eStart = offsets[nA], eEnd = offsets[nB];
    if (eStart >= eEnd) return;

    int cur = -1;
    float s0 = 0.f, s1 = 0.f, o0 = 0.f, o1 = 0.f;

    for (int base = eStart; base < eEnd; base += 16) {
        const int nv = min(16, eEnd - base);
        const int2 rc = rc2[min(base + low, eEnd - 1)];

        // ----- fragments: relu(Uh[r]-Vh[c]) in packed fp16 (v_pk_add/max) -----
        const f16x8* up = (const f16x8*)(Uh + (size_t)rc.x * 128);
        const f16x8* vp = (const f16x8*)(Vh + (size_t)rc.y * 128);
        const f16x8 zf = {};
        f16x8 hf[4];
#pragma unroll
        for (int kc = 0; kc < 4; ++kc) {
            f16x8 d = up[kc * 4 + g] - vp[kc * 4 + g];
            hf[kc] = __builtin_elementwise_max(d, zf);
        }

        // ----- mv2: alpha = h @ W2 (f16 MFMA) -----
        f32x4 acc[8];
#pragma unroll
        for (int nb = 0; nb < 8; ++nb) { acc[nb][0]=0.f; acc[nb][1]=0.f; acc[nb][2]=0.f; acc[nb][3]=0.f; }
#pragma unroll
        for (int nb = 0; nb < 8; ++nb) {
            int j = nb * 16 + low;
#pragma unroll
            for (int kc = 0; kc < 4; ++kc) {
                f16x8 bfv = *(const f16x8*)&wl[j * 128 + (((kc * 4 + g) ^ low) << 3)];
                acc[nb] = __builtin_amdgcn_mfma_f32_16x16x32_f16(hf[kc], bfv, acc[nb], 0, 0, 0);
            }
        }

        // ----- exp + transpose via wave-private LDS (rotated, conflict-light) -----
#pragma unroll
        for (int nb = 0; nb < 4; ++nb) {
#pragma unroll
            for (int r = 0; r < 4; ++r) {
                int e = g * 4 + r;
                float e0 = __expf(acc[nb][r] + b2v[nb]);
                float e1 = __expf(acc[nb + 4][r] + b2v[nb + 4]);
                wtile[w][e * 64 + ((nb * 16 + low + 4 * e) & 63)] =
                    (unsigned)f2bf(e0) | ((unsigned)f2bf(e1) << 16);
            }
        }

        // ----- prefetch Xc2 rows (coalesced: lane l reads dword l of row c_e) -----
        unsigned xv[16];
#pragma unroll
        for (int e = 0; e < 16; ++e) {
            if (e < nv) {
                int ce = __shfl(rc.y, e);
                xv[e] = Xc2[(size_t)ce * 64 + l];
            }
        }

        // ----- serial segmented accumulate (wave-uniform control) -----
#pragma unroll
        for (int e = 0; e < 16; ++e) {
            if (e < nv) {
                int re_ = __shfl(rc.x, e);
                if (re_ != cur) {
                    if (cur >= 0) {
                        float p0 = pos[cur * 3], p1 = pos[cur * 3 + 1], p2 = pos[cur * 3 + 2];
                        float pb0 = bp0 + p0 * wa0 + p1 * wa1 + p2 * wa2c;
                        float pb1 = bp1 + p0 * wb0 + p1 * wb1 + p2 * wb2;
                        out[(size_t)cur * 128 + l]      = (o0 + pb0 * s0) / (s0 + EPSV);
                        out[(size_t)cur * 128 + l + 64] = (o1 + pb1 * s1) / (s1 + EPSV);
                    }
                    s0 = s1 = o0 = o1 = 0.f;
                    cur = re_;
                }
                unsigned wv_ = wtile[w][e * 64 + ((l + 4 * e) & 63)];
                float w0 = bf2f(wv_ & 0xffffu), w1 = bf2f_hi(wv_);
                float x0 = bf2f(xv[e] & 0xffffu), x1 = bf2f_hi(xv[e]);
                s0 += w0; o0 = fmaf(w0, x0, o0);
                s1 += w1; o1 = fmaf(w1, x1, o1);
            }
        }
    }
    if (cur >= 0) {
        float p0 = pos[cur * 3], p1 = pos[cur * 3 + 1], p2 = pos[cur * 3 + 2];
        float pb0 = bp0 + p0 * wa0 + p1 * wa1 + p2 * wa2c;
        float pb1 = bp1 + p0 * wb0 + p1 * wb1 + p2 * wb2;
        out[(size_t)cur * 128 + l]      = (o0 + pb0 * s0) / (s0 + EPSV);
        out[(size_t)cur * 128 + l + 64] = (o1 + pb1 * s1) / (s1 + EPSV);
    }
}

extern "C" void kernel_launch(void* const* d_in, const int* in_sizes, int n_in,
                              void* d_out, int out_size, void* d_ws, size_t ws_size,
                              hipStream_t stream)
{
    const float* x    = (const float*)d_in[0];
    const float* pos  = (const float*)d_in[1];
    const int*   ei   = (const int*)d_in[2];
    const float* W    = (const float*)d_in[3];
    const float* Wsrc = (const float*)d_in[4];
    const float* Wdst = (const float*)d_in[5];
    const float* Wpos = (const float*)d_in[6];
    const float* bpos = (const float*)d_in[7];
    const float* Wa1  = (const float*)d_in[8];
    const float* ba1  = (const float*)d_in[9];
    const float* Wa2  = (const float*)d_in[10];
    const float* ba2  = (const float*)d_in[11];
    float* out = (float*)d_out;

    // ws: Uh/Vh fp16 (25.6MB) + Xc2 (12.8MB) + rc2 (4MB) + weights + CSR ints ~= 47MB
    ushort* Uh = (ushort*)d_ws;
    ushort* Vh = Uh + (size_t)NN * DD;
    unsigned* Xc2 = (unsigned*)(Vh + (size_t)NN * DD);
    int2* rc2 = (int2*)(Xc2 + (size_t)NN * 64);
    float* W1s = (float*)(rc2 + NE);
    float* W1d = W1s + 128 * 128;
    float* Wp1 = W1d + 128 * 128;
    float* b1eff = Wp1 + 384;
    int* offsets = (int*)(b1eff + 128);
    int* cursor  = offsets + (NN + 1);
    int* counts  = cursor + NN;
    int* partial = counts + NN;
    int* sn      = partial + 256;

    compose_kernel<<<16, 256, 0, stream>>>(Wsrc, Wdst, Wa1, Wpos, bpos, ba1, W1s, W1d, Wp1, b1eff);
    node_gemm<<<(NN + 63) / 64, 256, 0, stream>>>(
        x, pos, W, W1s, W1d, Wpos, Wp1, b1eff, Uh, Vh, Xc2);
    (void)hipMemsetAsync(counts, 0, NN * sizeof(int), stream);
    (void)hipMemsetAsync(out, 0, (size_t)NN * DD * sizeof(float), stream);
    hist_kernel<<<(NE + 255) / 256, 256, 0, stream>>>(ei, counts);
    csr_partial<<<256, 256, 0, stream>>>(counts, partial);
    csr_scanp<<<1, 256, 0, stream>>>(partial, offsets);
    csr_distribute<<<256, 256, 0, stream>>>(counts, partial, offsets, cursor);
    scatter_kernel<<<(NE + 255) / 256, 256, 0, stream>>>(ei, cursor, rc2);
    range_kernel<<<(NWAVE + 256) / 256, 256, 0, stream>>>(offsets, sn);
    fused_edge<<<NWAVE / 4, 256, 0, stream>>>(Uh, Vh, Wa2, ba2, pos, Wpos, bpos,
                                              rc2, offsets, sn, Xc2, out);
}

// Round 9
// 227.594 us; speedup vs baseline: 1.4357x; 1.4357x over previous
//
#include <hip/hip_runtime.h>
#include <hip/hip_fp16.h>
#include <math.h>

#define NN 50000
#define NE 500000
#define NTILES 31250   // NE/16 exact
#define DD 128
#define EPSV 1e-12f
#define SCC 196        // scan chunk per block (256*196 >= NN)
#define LOG2E 1.44269504088896f

typedef short short8 __attribute__((ext_vector_type(8)));
typedef _Float16 f16x8 __attribute__((ext_vector_type(8)));
typedef float f32x4 __attribute__((ext_vector_type(4)));

__device__ __forceinline__ ushort f2bf(float f) {
    return __builtin_bit_cast(unsigned short, (__bf16)f);
}
__device__ __forceinline__ ushort f2h(float f) {
    return __builtin_bit_cast(unsigned short, (_Float16)f);
}
__device__ __forceinline__ float bf2f(unsigned u) {
    union { unsigned u; float f; } v; v.u = u << 16;
    return v.f;
}
__device__ __forceinline__ float bf2f_hi(unsigned u) {
    union { unsigned u; float f; } v; v.u = u & 0xffff0000u;
    return v.f;
}

// ---------------- Kernel 0: weight composition (fp32) ----------------
// W1s = Wsrc@Wa1 ; W1d = Wdst@Wa1 ; Wp1 = Wpos@Wa1 ; b1eff = bpos@Wa1 + ba1
__global__ __launch_bounds__(256) void compose_kernel(
    const float* __restrict__ Wsrc, const float* __restrict__ Wdst,
    const float* __restrict__ Wa1, const float* __restrict__ Wpos,
    const float* __restrict__ bpos, const float* __restrict__ ba1,
    float* __restrict__ W1s, float* __restrict__ W1d,
    float* __restrict__ Wp1, float* __restrict__ b1eff)
{
    __shared__ float a1[128 * 8];
    const int t = threadIdx.x;
    const int j0 = blockIdx.x * 8;
    for (int idx = t; idx < 1024; idx += 256) {
        int i = idx >> 3, jl = idx & 7;
        a1[idx] = Wa1[i * 128 + j0 + jl];
    }
    __syncthreads();
    const int jl = t & 7, k0 = t >> 3;
#pragma unroll 1
    for (int kb = 0; kb < 4; ++kb) {
        int k = kb * 32 + k0;
        float s1 = 0.f, s2 = 0.f;
        for (int i = 0; i < 128; ++i) {
            float w = a1[i * 8 + jl];
            s1 = fmaf(Wsrc[k * 128 + i], w, s1);
            s2 = fmaf(Wdst[k * 128 + i], w, s2);
        }
        W1s[k * 128 + j0 + jl] = s1;
        W1d[k * 128 + j0 + jl] = s2;
    }
    if (t < 32) {
        int d = t >> 3, j = j0 + (t & 7);
        float s = 0.f;
        if (d < 3) {
            for (int i = 0; i < 128; ++i) s = fmaf(Wpos[d * 128 + i], a1[i * 8 + (t & 7)], s);
            Wp1[d * 128 + j] = s;
        } else {
            for (int i = 0; i < 128; ++i) s = fmaf(bpos[i], a1[i * 8 + (t & 7)], s);
            b1eff[j] = s + ba1[j];
        }
    }
}

// ---------------- Kernel 1: node GEMMs, 3 phases fused ----------------
// y=0: Uh(fp16) = x@W1s + pos@Wp1 + b1eff
// y=1: Vh(fp16) = x@W1d + pos@Wp1
// y=2: Xc2(packed bf16 dword (ch,ch+64)) = x@W - pos@Wpos
__global__ __launch_bounds__(256) void node_gemm(
    const float* __restrict__ x, const float* __restrict__ pos,
    const float* __restrict__ W, const float* __restrict__ W1s,
    const float* __restrict__ W1d, const float* __restrict__ Wpos,
    const float* __restrict__ Wp1, const float* __restrict__ b1eff,
    ushort* __restrict__ Uh, ushort* __restrict__ Vh, unsigned* __restrict__ Xc2)
{
    __shared__ ushort wsm[16384];
    const int t = threadIdx.x;
    const int w = t >> 6;
    const int l = t & 63;
    const int g = l >> 4;
    const int low = l & 15;

    const int n0 = (blockIdx.x * 4 + w) * 16;
    const int rowi = min(n0 + low, NN - 1);

    short8 af[4];
#pragma unroll
    for (int kc = 0; kc < 4; ++kc) {
        const float* xp = x + (size_t)rowi * 128 + kc * 32 + g * 8;
        float4 a0 = *(const float4*)xp;
        float4 a1 = *(const float4*)(xp + 4);
        short8 v;
        v[0] = (short)f2bf(a0.x); v[1] = (short)f2bf(a0.y);
        v[2] = (short)f2bf(a0.z); v[3] = (short)f2bf(a0.w);
        v[4] = (short)f2bf(a1.x); v[5] = (short)f2bf(a1.y);
        v[6] = (short)f2bf(a1.z); v[7] = (short)f2bf(a1.w);
        af[kc] = v;
    }
    float posr[4][3];
#pragma unroll
    for (int r = 0; r < 4; ++r) {
        int node = min(n0 + g * 4 + r, NN - 1);
        posr[r][0] = pos[node * 3]; posr[r][1] = pos[node * 3 + 1]; posr[r][2] = pos[node * 3 + 2];
    }

#pragma unroll 1
    for (int y = 0; y < 3; ++y) {
        const float* Wsel = (y == 0) ? W1s : (y == 1) ? W1d : W;
        const float* wps  = (y < 2) ? Wp1 : Wpos;

        for (int gi = t; gi < 2048; gi += 256) {
            int j = gi & 127, k8 = gi >> 7;
            short8 v;
#pragma unroll
            for (int i = 0; i < 8; ++i)
                v[i] = (short)f2bf(Wsel[(k8 * 8 + i) * 128 + j]);
            *(short8*)&wsm[j * 128 + ((k8 ^ (j & 15)) << 3)] = v;
        }
        float wp0[8], wp1v[8], wp2[8], bpv[8];
#pragma unroll
        for (int nb = 0; nb < 8; ++nb) {
            int ch = nb * 16 + low;
            wp0[nb] = wps[ch]; wp1v[nb] = wps[128 + ch]; wp2[nb] = wps[256 + ch];
            bpv[nb] = (y == 0) ? b1eff[ch] : 0.f;
        }
        __syncthreads();

        f32x4 acc[8];
#pragma unroll
        for (int nb = 0; nb < 8; ++nb) { acc[nb][0]=0.f; acc[nb][1]=0.f; acc[nb][2]=0.f; acc[nb][3]=0.f; }
#pragma unroll
        for (int nb = 0; nb < 8; ++nb) {
            int j = nb * 16 + low;
#pragma unroll
            for (int kc = 0; kc < 4; ++kc) {
                short8 bf = *(const short8*)&wsm[j * 128 + (((kc * 4 + g) ^ low) << 3)];
                acc[nb] = __builtin_amdgcn_mfma_f32_16x16x32_bf16(af[kc], bf, acc[nb], 0, 0, 0);
            }
        }

#pragma unroll
        for (int r = 0; r < 4; ++r) {
            int node = n0 + g * 4 + r;
            if (node < NN) {
                float p0 = posr[r][0], p1 = posr[r][1], p2 = posr[r][2];
                if (y < 2) {
#pragma unroll
                    for (int nb = 0; nb < 8; ++nb) {
                        float pterm = p0 * wp0[nb] + p1 * wp1v[nb] + p2 * wp2[nb];
                        size_t idx = (size_t)node * 128 + nb * 16 + low;
                        if (y == 0) Uh[idx] = f2h(acc[nb][r] + pterm + bpv[nb]);
                        else        Vh[idx] = f2h(acc[nb][r] + pterm);
                    }
                } else {
#pragma unroll
                    for (int nb = 0; nb < 4; ++nb) {
                        float ptl = p0 * wp0[nb] + p1 * wp1v[nb] + p2 * wp2[nb];
                        float pth = p0 * wp0[nb+4] + p1 * wp1v[nb+4] + p2 * wp2[nb+4];
                        Xc2[(size_t)node * 64 + nb * 16 + low] =
                            (unsigned)f2bf(acc[nb][r] - ptl) | ((unsigned)f2bf(acc[nb+4][r] - pth) << 16);
                    }
                }
            }
        }
        __syncthreads();
    }
}

// ---------------- CSR build ----------------
__global__ __launch_bounds__(256) void hist_kernel(const int* __restrict__ ei, int* __restrict__ counts)
{
    int e = blockIdx.x * 256 + threadIdx.x;
    if (e < NE) atomicAdd(&counts[ei[2 * e]], 1);
}

__global__ __launch_bounds__(256) void csr_partial(const int* __restrict__ counts, int* __restrict__ partial)
{
    __shared__ int red[256];
    const int b = blockIdx.x, t = threadIdx.x;
    const int idx = b * SCC + t;
    red[t] = (t < SCC && idx < NN) ? counts[idx] : 0;
    __syncthreads();
#pragma unroll
    for (int d = 128; d > 0; d >>= 1) {
        if (t < d) red[t] += red[t + d];
        __syncthreads();
    }
    if (t == 0) partial[b] = red[0];
}

__global__ __launch_bounds__(256) void csr_scanp(int* __restrict__ partial, int* __restrict__ offsets)
{
    __shared__ int s[256];
    const int t = threadIdx.x;
    int v = partial[t];
    s[t] = v;
    __syncthreads();
    for (int d = 1; d < 256; d <<= 1) {
        int u = (t >= d) ? s[t - d] : 0;
        __syncthreads();
        s[t] += u;
        __syncthreads();
    }
    partial[t] = s[t] - v;
    if (t == 255) offsets[NN] = s[255];
}

__global__ __launch_bounds__(256) void csr_distribute(
    const int* __restrict__ counts, const int* __restrict__ partial,
    int* __restrict__ offsets, int* __restrict__ cursor)
{
    __shared__ int s[256];
    const int b = blockIdx.x, t = threadIdx.x;
    const int idx = b * SCC + t;
    int v = (t < SCC && idx < NN) ? counts[idx] : 0;
    s[t] = v;
    __syncthreads();
    for (int d = 1; d < 256; d <<= 1) {
        int u = (t >= d) ? s[t - d] : 0;
        __syncthreads();
        s[t] += u;
        __syncthreads();
    }
    if (t < SCC && idx < NN) {
        int off = partial[b] + s[t] - v;
        offsets[idx] = off;
        cursor[idx] = off;
    }
}

__global__ __launch_bounds__(256) void scatter_kernel(const int* __restrict__ ei,
                                                      int* __restrict__ cursor,
                                                      int2* __restrict__ rc2, int* __restrict__ colc)
{
    int e = blockIdx.x * 256 + threadIdx.x;
    if (e < NE) {
        int r = ei[2 * e];
        int c = ei[2 * e + 1];
        int p = atomicAdd(&cursor[r], 1);
        rc2[p] = make_int2(r, c);
        colc[p] = c;
    }
}

// ---------------- Pass A: expW = exp(relu(Uh[r]-Vh[c]) @ W2L + b2L), packed (ch,ch+64) ----------------
// W2L = Wa2 * log2e staged in LDS (fp16); exp via exp2f (bare v_exp_f32).
// Pair-wise accumulators (p, p+4): only 16 acc VGPRs live -> high occupancy.
__global__ __launch_bounds__(256) void expalpha_kernel(
    const ushort* __restrict__ Uh, const ushort* __restrict__ Vh,
    const float* __restrict__ Wa2, const float* __restrict__ ba2,
    const int2* __restrict__ rc2,
    unsigned* __restrict__ expW)
{
    __shared__ ushort wl[16384];

    const int t = threadIdx.x;
    const int w = t >> 6;
    const int l = t & 63;
    const int g = l >> 4;
    const int low = l & 15;

    for (int gi = t; gi < 2048; gi += 256) {
        int j = gi & 127, k8 = gi >> 7;
        short8 v;
#pragma unroll
        for (int i = 0; i < 8; ++i)
            v[i] = (short)f2h(Wa2[(k8 * 8 + i) * 128 + j] * LOG2E);
        *(short8*)&wl[j * 128 + ((k8 ^ (j & 15)) << 3)] = v;
    }
    float b2l[4], b2h[4];
#pragma unroll
    for (int p = 0; p < 4; ++p) {
        b2l[p] = ba2[p * 16 + low] * LOG2E;
        b2h[p] = ba2[p * 16 + 64 + low] * LOG2E;
    }
    __syncthreads();

    const int nw = gridDim.x * 4;
    const int w0 = blockIdx.x * 4 + w;

    for (int t0 = w0; t0 < NTILES; t0 += 2 * nw) {
        const int t1 = t0 + nw;
        const bool has1 = t1 < NTILES;

        // ----- gather fragments: relu(Uh[r]-Vh[c]) in packed fp16 -----
        const f16x8 zf = {};
        f16x8 hfA[4], hfB[4];
        {
            int2 rc = rc2[t0 * 16 + low];
            const f16x8* up = (const f16x8*)(Uh + (size_t)rc.x * 128);
            const f16x8* vp = (const f16x8*)(Vh + (size_t)rc.y * 128);
#pragma unroll
            for (int kc = 0; kc < 4; ++kc) {
                f16x8 d = up[kc * 4 + g] - vp[kc * 4 + g];
                hfA[kc] = __builtin_elementwise_max(d, zf);
            }
        }
        if (has1) {
            int2 rc = rc2[t1 * 16 + low];
            const f16x8* up = (const f16x8*)(Uh + (size_t)rc.x * 128);
            const f16x8* vp = (const f16x8*)(Vh + (size_t)rc.y * 128);
#pragma unroll
            for (int kc = 0; kc < 4; ++kc) {
                f16x8 d = up[kc * 4 + g] - vp[kc * 4 + g];
                hfB[kc] = __builtin_elementwise_max(d, zf);
            }
        }

        // ----- per channel-pair: MFMA + exp2 + packed store -----
#pragma unroll
        for (int p = 0; p < 4; ++p) {
            const int jA = p * 16 + low;
            const int jB = (p + 4) * 16 + low;
            f32x4 aA0 = {0.f,0.f,0.f,0.f}, aA1 = {0.f,0.f,0.f,0.f};
            f32x4 aB0 = {0.f,0.f,0.f,0.f}, aB1 = {0.f,0.f,0.f,0.f};
#pragma unroll
            for (int kc = 0; kc < 4; ++kc) {
                int soff = ((kc * 4 + g) ^ low) << 3;
                f16x8 bf0 = *(const f16x8*)&wl[jA * 128 + soff];
                f16x8 bf1 = *(const f16x8*)&wl[jB * 128 + soff];
                aA0 = __builtin_amdgcn_mfma_f32_16x16x32_f16(hfA[kc], bf0, aA0, 0, 0, 0);
                aA1 = __builtin_amdgcn_mfma_f32_16x16x32_f16(hfA[kc], bf1, aA1, 0, 0, 0);
                if (has1) {
                    aB0 = __builtin_amdgcn_mfma_f32_16x16x32_f16(hfB[kc], bf0, aB0, 0, 0, 0);
                    aB1 = __builtin_amdgcn_mfma_f32_16x16x32_f16(hfB[kc], bf1, aB1, 0, 0, 0);
                }
            }
#pragma unroll
            for (int r = 0; r < 4; ++r) {
                float e0 = exp2f(aA0[r] + b2l[p]);
                float e1 = exp2f(aA1[r] + b2h[p]);
                expW[(size_t)(t0 * 16 + g * 4 + r) * 64 + p * 16 + low] =
                    (unsigned)f2bf(e0) | ((unsigned)f2bf(e1) << 16);
                if (has1) {
                    float f0 = exp2f(aB0[r] + b2l[p]);
                    float f1 = exp2f(aB1[r] + b2h[p]);
                    expW[(size_t)(t1 * 16 + g * 4 + r) * 64 + p * 16 + low] =
                        (unsigned)f2bf(f0) | ((unsigned)f2bf(f1) << 16);
                }
            }
        }
    }
}

// ---------------- Pass B: single-pass per-node weighted aggregate ----------------
__global__ __launch_bounds__(256) void aggregate_kernel(
    const float* __restrict__ pos,
    const float* __restrict__ Wpos, const float* __restrict__ bpos,
    const unsigned* __restrict__ Xc2,
    const int* __restrict__ offsets, const int* __restrict__ colc,
    const unsigned* __restrict__ expW, float* __restrict__ out)
{
    const int l = threadIdx.x & 63;
    const int wid = blockIdx.x * 4 + (threadIdx.x >> 6);
    const int nw = gridDim.x * 4;

    const float wpa0 = Wpos[l], wpa1 = Wpos[128 + l], wpa2 = Wpos[256 + l];
    const float wpb0 = Wpos[64 + l], wpb1 = Wpos[192 + l], wpb2 = Wpos[320 + l];
    const float bpa = bpos[l], bpb = bpos[64 + l];

    for (int node = wid; node < NN; node += nw) {
        const int aoff = offsets[node];
        const int deg = offsets[node + 1] - aoff;
        const unsigned* ap = expW + (size_t)aoff * 64 + l;

        float s0 = 0.f, s1 = 0.f, o0 = 0.f, o1 = 0.f;
#pragma unroll 4
        for (int e = 0; e < deg; ++e) {
            unsigned v = ap[(size_t)e * 64];
            int c = colc[aoff + e];
            unsigned xv = Xc2[(size_t)c * 64 + l];
            float w0 = bf2f(v & 0xffffu);
            float w1 = bf2f_hi(v);
            float xc0 = bf2f(xv & 0xffffu);
            float xc1 = bf2f_hi(xv);
            s0 += w0; o0 = fmaf(w0, xc0, o0);
            s1 += w1; o1 = fmaf(w1, xc1, o1);
        }
        float p0 = pos[node * 3], p1 = pos[node * 3 + 1], p2 = pos[node * 3 + 2];
        float pb0 = bpa + p0 * wpa0 + p1 * wpa1 + p2 * wpa2;
        float pb1 = bpb + p0 * wpb0 + p1 * wpb1 + p2 * wpb2;
        out[(size_t)node * 128 + l]      = (o0 + pb0 * s0) / (s0 + EPSV);
        out[(size_t)node * 128 + l + 64] = (o1 + pb1 * s1) / (s1 + EPSV);
    }
}

extern "C" void kernel_launch(void* const* d_in, const int* in_sizes, int n_in,
                              void* d_out, int out_size, void* d_ws, size_t ws_size,
                              hipStream_t stream)
{
    const float* x    = (const float*)d_in[0];
    const float* pos  = (const float*)d_in[1];
    const int*   ei   = (const int*)d_in[2];
    const float* W    = (const float*)d_in[3];
    const float* Wsrc = (const float*)d_in[4];
    const float* Wdst = (const float*)d_in[5];
    const float* Wpos = (const float*)d_in[6];
    const float* bpos = (const float*)d_in[7];
    const float* Wa1  = (const float*)d_in[8];
    const float* ba1  = (const float*)d_in[9];
    const float* Wa2  = (const float*)d_in[10];
    const float* ba2  = (const float*)d_in[11];
    float* out = (float*)d_out;

    // ws: Uh/Vh fp16 (25.6MB) + Xc2 (12.8MB) + weights + CSR + rc2 + colc + expW (128MB) ~= 177MB
    ushort* Uh = (ushort*)d_ws;
    ushort* Vh = Uh + (size_t)NN * DD;
    unsigned* Xc2 = (unsigned*)(Vh + (size_t)NN * DD);
    float* W1s = (float*)(Xc2 + (size_t)NN * 64);
    float* W1d = W1s + 128 * 128;
    float* Wp1 = W1d + 128 * 128;
    float* b1eff = Wp1 + 384;
    int* offsets = (int*)(b1eff + 128);
    int* cursor  = offsets + (NN + 1);
    int* counts  = cursor + NN;
    int* partial = counts + NN;
    int* colc    = partial + 256;
    int2* rc2    = (int2*)(colc + NE);
    unsigned* expW = (unsigned*)(rc2 + NE);

    compose_kernel<<<16, 256, 0, stream>>>(Wsrc, Wdst, Wa1, Wpos, bpos, ba1, W1s, W1d, Wp1, b1eff);
    node_gemm<<<(NN + 63) / 64, 256, 0, stream>>>(
        x, pos, W, W1s, W1d, Wpos, Wp1, b1eff, Uh, Vh, Xc2);
    (void)hipMemsetAsync(counts, 0, NN * sizeof(int), stream);
    hist_kernel<<<(NE + 255) / 256, 256, 0, stream>>>(ei, counts);
    csr_partial<<<256, 256, 0, stream>>>(counts, partial);
    csr_scanp<<<1, 256, 0, stream>>>(partial, offsets);
    csr_distribute<<<256, 256, 0, stream>>>(counts, partial, offsets, cursor);
    scatter_kernel<<<(NE + 255) / 256, 256, 0, stream>>>(ei, cursor, rc2, colc);
    expalpha_kernel<<<2048, 256, 0, stream>>>(Uh, Vh, Wa2, ba2, rc2, expW);
    aggregate_kernel<<<4096, 256, 0, stream>>>(pos, Wpos, bpos, Xc2, offsets, colc, expW, out);
}